// Round 2
// baseline (7691.772 us; speedup 1.0000x reference)
//
#include <hip/hip_runtime.h>
#include <math.h>

// HierarchicalManifold, v2: fully fused, 256 threads (4 waves) per batch element.
// Per-thread register arrays kept <= 32 floats, all statically indexed (no scratch).
// LDS 38.4 KB -> 4 blocks/CU -> 16 waves/CU.
//
// Thread roles (t = 0..255):
//   micro-row ops : r = t>>2 (0..63), s = t&3, cols cs = 8s..8s+7
//   trace/qw ops  : dtr = t>>3 (0..31), j8 = t&7, cols e4 = 4*j8
//   macro ops     : mq = t>>4 (0..15), mj = t&15, cols c2 = 2*mj
//   attn ops      : hq = t>>3 (0..31) = (h,q), k in {j8, j8+8, ..., j8+56}

#define NMI 64
#define NMA 16
#define DD  32
#define NH  2
#define DHH 16
#define EH  64
#define SP  36    // padded LDS stride

#define F4(p_) (*(const float4*)(p_))
#define F2(p_) (*(const float2*)(p_))

struct HMParams {
    const float* micro; const float* macro_; const float* tmi; const float* tma;
    const float* W_td; const float* b_td; const float* ln_g; const float* ln_b;
    const float* Wqkv; const float* bqkv; const float* Wo; const float* bo;
    const float* A_mi; const float* Ws_mi; const float* Wa_mi; const float* b_mi;
    const float* A_ma; const float* Ws_ma; const float* Wa_ma; const float* b_ma;
    const float* We1; const float* be1; const float* We2; const float* be2;
    const int* steps;
    float* out;
};

__device__ __forceinline__ float fast_tanh(float x) {
    float e = __expf(2.0f * x);
    return 1.0f - 2.0f / (e + 1.0f);
}

__global__ __launch_bounds__(256, 4) void hm_fused(HMParams p) {
    const int bid = blockIdx.x;
    const int t   = threadIdx.x;

    __shared__ float SA[NMI][SP];     // micro state ping
    __shared__ float SB[NMI][SP];     // micro state pong (also agg scratch, then vp)
    __shared__ float Tmi[DD][DD];
    __shared__ float Tma[DD][DD];
    __shared__ float M0[NMA][SP];     // macro state
    __shared__ float M1[NMA][SP];     // post-LN macro
    __shared__ float QP[NMA][SP];     // qp, then attn-out
    __shared__ float QW[DD][SP];      // TW (=Tmi+Ws_mi) in P4; qw in P6/P7; AG rows 0..15 in P9/P10
    __shared__ float misc[64];        // colmean/bias, later qb[32], later energy partials

    const int r   = t >> 2;
    const int s   = t & 3;
    const int cs  = s * 8;
    const int dtr = t >> 3;
    const int j8  = t & 7;
    const int e4  = j8 * 4;
    const int mq  = t >> 4;
    const int mj  = t & 15;
    const int c2  = mj * 2;

    // ---------------- load ----------------
    {
        const float* g = p.micro + (size_t)bid * (NMI * DD) + r * DD + cs;
        *(float4*)&SA[r][cs]     = F4(g);
        *(float4*)&SA[r][cs + 4] = F4(g + 4);
        const float* gt = p.tmi + (size_t)bid * (DD * DD) + dtr * DD + e4;
        *(float4*)&Tmi[dtr][e4] = F4(gt);
        gt = p.tma + (size_t)bid * (DD * DD) + dtr * DD + e4;
        *(float4*)&Tma[dtr][e4] = F4(gt);
        if (t < 128) {
            int q_ = t >> 3, c4 = (t & 7) * 4;
            *(float4*)&M0[q_][c4] =
                F4(p.macro_ + (size_t)bid * (NMA * DD) + q_ * DD + c4);
        }
    }
    const int nsteps = p.steps[0];
    __syncthreads();

    float (*Scur)[SP] = SA;
    float (*Snxt)[SP] = SB;

    for (int step = 0; step < nsteps; ++step) {
        // ---- P1: macro column means ----
        if (t < DD) {
            float a = 0.f;
            #pragma unroll
            for (int n = 0; n < NMA; ++n) a += M0[n][t];
            misc[t] = a * (1.0f / NMA);
        }
        __syncthreads();
        // ---- P2: 0.1 * (colmean @ W_td^T + b_td) ----
        if (t < DD) {
            float a = p.b_td[t];
            #pragma unroll
            for (int d4 = 0; d4 < 8; ++d4) {
                float4 w = F4(&p.W_td[t * DD + 4 * d4]);
                float4 m = F4(&misc[4 * d4]);
                a += m.x*w.x + m.y*w.y + m.z*w.z + m.w*w.w;
            }
            misc[DD + t] = 0.1f * a;
        }
        __syncthreads();
        // ---- P3: micro += bias (in place); TW = Tmi + Ws_mi -> QW ----
        {
            float4 b0 = F4(&misc[DD + cs]), b1 = F4(&misc[DD + cs + 4]);
            float4 v0 = F4(&Scur[r][cs]),   v1 = F4(&Scur[r][cs + 4]);
            v0.x += b0.x; v0.y += b0.y; v0.z += b0.z; v0.w += b0.w;
            v1.x += b1.x; v1.y += b1.y; v1.z += b1.z; v1.w += b1.w;
            *(float4*)&Scur[r][cs]     = v0;
            *(float4*)&Scur[r][cs + 4] = v1;
            float4 tv = F4(&Tmi[dtr][e4]);
            float4 wv = F4(&p.Ws_mi[dtr * DD + e4]);
            tv.x += wv.x; tv.y += wv.y; tv.z += wv.z; tv.w += wv.w;
            *(float4*)&QW[dtr][e4] = tv;
        }
        __syncthreads();

        // ---- P4a: micro automata: heb+Ws (via TW), agg partial -> Snxt ----
        float rowv[DD];   // full S_in row (live through P4c)
        float own[8];     // this thread's 8 cols of S_in
        float accv[8];
        {
            #pragma unroll
            for (int d4 = 0; d4 < 8; ++d4)
                *(float4*)&rowv[4 * d4] = F4(&Scur[r][4 * d4]);
            {
                float4 o0 = F4(&Scur[r][cs]), o1 = F4(&Scur[r][cs + 4]);
                own[0]=o0.x; own[1]=o0.y; own[2]=o0.z; own[3]=o0.w;
                own[4]=o1.x; own[5]=o1.y; own[6]=o1.z; own[7]=o1.w;
            }
            {
                float4 b0 = F4(&p.b_mi[cs]), b1 = F4(&p.b_mi[cs + 4]);
                accv[0]=b0.x; accv[1]=b0.y; accv[2]=b0.z; accv[3]=b0.w;
                accv[4]=b1.x; accv[5]=b1.y; accv[6]=b1.z; accv[7]=b1.w;
            }
            // acc += sum_d row[d] * TW[d][cs..cs+7]
            #pragma unroll
            for (int d = 0; d < DD; ++d) {
                float sd = rowv[d];
                float4 t0 = F4(&QW[d][cs]);
                float4 t1 = F4(&QW[d][cs + 4]);
                accv[0]+=sd*t0.x; accv[1]+=sd*t0.y; accv[2]+=sd*t0.z; accv[3]+=sd*t0.w;
                accv[4]+=sd*t1.x; accv[5]+=sd*t1.y; accv[6]+=sd*t1.z; accv[7]+=sd*t1.w;
            }
            // agg partial: agg[j] = sum_n A_mi[r][n] * S_in[n][cs+j]
            float aggv[8] = {0,0,0,0,0,0,0,0};
            #pragma unroll 4
            for (int n4 = 0; n4 < 16; ++n4) {
                float4 a4 = F4(&p.A_mi[r * NMI + 4 * n4]);
                const float* r0 = Scur[4*n4+0];
                const float* r1 = Scur[4*n4+1];
                const float* r2 = Scur[4*n4+2];
                const float* r3 = Scur[4*n4+3];
                float4 x, y;
                x = F4(r0+cs); y = F4(r0+cs+4);
                aggv[0]+=a4.x*x.x; aggv[1]+=a4.x*x.y; aggv[2]+=a4.x*x.z; aggv[3]+=a4.x*x.w;
                aggv[4]+=a4.x*y.x; aggv[5]+=a4.x*y.y; aggv[6]+=a4.x*y.z; aggv[7]+=a4.x*y.w;
                x = F4(r1+cs); y = F4(r1+cs+4);
                aggv[0]+=a4.y*x.x; aggv[1]+=a4.y*x.y; aggv[2]+=a4.y*x.z; aggv[3]+=a4.y*x.w;
                aggv[4]+=a4.y*y.x; aggv[5]+=a4.y*y.y; aggv[6]+=a4.y*y.z; aggv[7]+=a4.y*y.w;
                x = F4(r2+cs); y = F4(r2+cs+4);
                aggv[0]+=a4.z*x.x; aggv[1]+=a4.z*x.y; aggv[2]+=a4.z*x.z; aggv[3]+=a4.z*x.w;
                aggv[4]+=a4.z*y.x; aggv[5]+=a4.z*y.y; aggv[6]+=a4.z*y.z; aggv[7]+=a4.z*y.w;
                x = F4(r3+cs); y = F4(r3+cs+4);
                aggv[0]+=a4.w*x.x; aggv[1]+=a4.w*x.y; aggv[2]+=a4.w*x.z; aggv[3]+=a4.w*x.w;
                aggv[4]+=a4.w*y.x; aggv[5]+=a4.w*y.y; aggv[6]+=a4.w*y.z; aggv[7]+=a4.w*y.w;
            }
            *(float4*)&Snxt[r][cs]     = make_float4(aggv[0],aggv[1],aggv[2],aggv[3]);
            *(float4*)&Snxt[r][cs + 4] = make_float4(aggv[4],aggv[5],aggv[6],aggv[7]);
        }
        __syncthreads();
        // ---- P4c: + agg@Wa, tanh, l2norm -> Snxt ----
        {
            float aggrow[DD];
            #pragma unroll
            for (int d4 = 0; d4 < 8; ++d4)
                *(float4*)&aggrow[4 * d4] = F4(&Snxt[r][4 * d4]);
            #pragma unroll
            for (int d = 0; d < DD; ++d) {
                float ad = aggrow[d];
                float4 w0 = F4(&p.Wa_mi[d * DD + cs]);
                float4 w1 = F4(&p.Wa_mi[d * DD + cs + 4]);
                accv[0]+=ad*w0.x; accv[1]+=ad*w0.y; accv[2]+=ad*w0.z; accv[3]+=ad*w0.w;
                accv[4]+=ad*w1.x; accv[5]+=ad*w1.y; accv[6]+=ad*w1.z; accv[7]+=ad*w1.w;
            }
            float vv[8]; float ss = 0.f;
            #pragma unroll
            for (int j = 0; j < 8; ++j) {
                float v_ = own[j] + 0.1f * fast_tanh(accv[j]);
                vv[j] = v_; ss += v_ * v_;
            }
            ss += __shfl_xor(ss, 1); ss += __shfl_xor(ss, 2);
            float inv = 1.0f / (sqrtf(ss) + 1e-6f);
            #pragma unroll
            for (int j = 0; j < 8; ++j) vv[j] *= inv;
            __syncthreads();   // all reads of agg scratch done before overwrite
            *(float4*)&Snxt[r][cs]     = make_float4(vv[0],vv[1],vv[2],vv[3]);
            *(float4*)&Snxt[r][cs + 4] = make_float4(vv[4],vv[5],vv[6],vv[7]);
        }
        __syncthreads();

        // ---- P5: micro trace update + qp projection ----
        {
            float t0=0.f,t1=0.f,t2=0.f,t3=0.f;
            #pragma unroll 4
            for (int n = 0; n < NMI; ++n) {
                float pd = Scur[n][dtr];
                float4 v = F4(&Snxt[n][e4]);
                t0 += pd*v.x; t1 += pd*v.y; t2 += pd*v.z; t3 += pd*v.w;
            }
            float4 tv = F4(&Tmi[dtr][e4]);
            tv.x = 0.95f*tv.x + (0.05f/NMI)*t0;
            tv.y = 0.95f*tv.y + (0.05f/NMI)*t1;
            tv.z = 0.95f*tv.z + (0.05f/NMI)*t2;
            tv.w = 0.95f*tv.w + (0.05f/NMI)*t3;
            *(float4*)&Tmi[dtr][e4] = tv;
        }
        {
            float mrow[DD];
            #pragma unroll
            for (int d4 = 0; d4 < 8; ++d4)
                *(float4*)&mrow[4 * d4] = F4(&M0[mq][4 * d4]);
            float q0 = p.bqkv[c2], q1 = p.bqkv[c2 + 1];
            #pragma unroll
            for (int d4 = 0; d4 < 8; ++d4) {
                float4 w0 = F4(&p.Wqkv[c2 * DD + 4 * d4]);
                float4 w1 = F4(&p.Wqkv[(c2 + 1) * DD + 4 * d4]);
                q0 += mrow[4*d4]*w0.x + mrow[4*d4+1]*w0.y + mrow[4*d4+2]*w0.z + mrow[4*d4+3]*w0.w;
                q1 += mrow[4*d4]*w1.x + mrow[4*d4+1]*w1.y + mrow[4*d4+2]*w1.z + mrow[4*d4+3]*w1.w;
            }
            *(float2*)&QP[mq][c2] = make_float2(q0, q1);
        }
        __syncthreads();

        // ---- P6: vp -> Scur; qw = 0.25*(qp@Wk) -> QW; qb -> misc ----
        {
            float rowB[DD];
            #pragma unroll
            for (int d4 = 0; d4 < 8; ++d4)
                *(float4*)&rowB[4 * d4] = F4(&Snxt[r][4 * d4]);
            float vv[8];
            {
                float4 b0 = F4(&p.bqkv[2*DD + cs]), b1 = F4(&p.bqkv[2*DD + cs + 4]);
                vv[0]=b0.x; vv[1]=b0.y; vv[2]=b0.z; vv[3]=b0.w;
                vv[4]=b1.x; vv[5]=b1.y; vv[6]=b1.z; vv[7]=b1.w;
            }
            #pragma unroll
            for (int j = 0; j < 8; ++j) {
                const float* wr = &p.Wqkv[(2*DD + cs + j) * DD];
                float a = 0.f;
                #pragma unroll
                for (int d4 = 0; d4 < 8; ++d4) {
                    float4 w = F4(wr + 4 * d4);
                    a += rowB[4*d4]*w.x + rowB[4*d4+1]*w.y + rowB[4*d4+2]*w.z + rowB[4*d4+3]*w.w;
                }
                vv[j] += a;
            }
            *(float4*)&Scur[r][cs]     = make_float4(vv[0],vv[1],vv[2],vv[3]);
            *(float4*)&Scur[r][cs + 4] = make_float4(vv[4],vv[5],vv[6],vv[7]);
        }
        {
            const int h_ = dtr >> 4, q_ = dtr & 15;
            float qpr[16];
            #pragma unroll
            for (int i4 = 0; i4 < 4; ++i4)
                *(float4*)&qpr[4 * i4] = F4(&QP[q_][h_ * DHH + 4 * i4]);
            float w0=0.f,w1=0.f,w2=0.f,w3=0.f;
            #pragma unroll
            for (int e = 0; e < 16; ++e) {
                float4 w = F4(&p.Wqkv[(DD + h_ * DHH + e) * DD + e4]);
                w0 += qpr[e]*w.x; w1 += qpr[e]*w.y; w2 += qpr[e]*w.z; w3 += qpr[e]*w.w;
            }
            *(float4*)&QW[dtr][e4] =
                make_float4(0.25f*w0, 0.25f*w1, 0.25f*w2, 0.25f*w3);
            if (j8 == 0) {
                float a = 0.f;
                #pragma unroll
                for (int e = 0; e < 16; ++e)
                    a += qpr[e] * p.bqkv[DD + h_ * DHH + e];
                misc[dtr] = 0.25f * a;
            }
        }
        __syncthreads();

        // ---- P7: scores + softmax + PV (8 threads per (h,q), k stride 8) ----
        {
            const int hq = dtr, h_ = hq >> 4, q_ = hq & 15;
            float qwr[DD];
            #pragma unroll
            for (int d4 = 0; d4 < 8; ++d4)
                *(float4*)&qwr[4 * d4] = F4(&QW[hq][4 * d4]);
            const float qb = misc[hq];
            float sc[8];
            #pragma unroll
            for (int kk = 0; kk < 8; ++kk) {
                const int k = j8 + 8 * kk;
                float a = qb;
                #pragma unroll
                for (int d4 = 0; d4 < 8; ++d4) {
                    float4 b4 = F4(&Snxt[k][4 * d4]);
                    a += qwr[4*d4]*b4.x + qwr[4*d4+1]*b4.y + qwr[4*d4+2]*b4.z + qwr[4*d4+3]*b4.w;
                }
                sc[kk] = a;
            }
            float mx = sc[0];
            #pragma unroll
            for (int kk = 1; kk < 8; ++kk) mx = fmaxf(mx, sc[kk]);
            mx = fmaxf(mx, __shfl_xor(mx, 1));
            mx = fmaxf(mx, __shfl_xor(mx, 2));
            mx = fmaxf(mx, __shfl_xor(mx, 4));
            float den = 0.f; float pr[8];
            #pragma unroll
            for (int kk = 0; kk < 8; ++kk) { pr[kk] = __expf(sc[kk] - mx); den += pr[kk]; }
            den += __shfl_xor(den, 1); den += __shfl_xor(den, 2); den += __shfl_xor(den, 4);
            float po[16];
            #pragma unroll
            for (int i = 0; i < 16; ++i) po[i] = 0.f;
            #pragma unroll
            for (int kk = 0; kk < 8; ++kk) {
                const int k = j8 + 8 * kk;
                const float pv = pr[kk];
                #pragma unroll
                for (int i4 = 0; i4 < 4; ++i4) {
                    float4 v = F4(&Scur[k][h_ * DHH + 4 * i4]);
                    po[4*i4+0] += pv*v.x; po[4*i4+1] += pv*v.y;
                    po[4*i4+2] += pv*v.z; po[4*i4+3] += pv*v.w;
                }
            }
            #pragma unroll
            for (int i = 0; i < 16; ++i) {
                po[i] += __shfl_xor(po[i], 1);
                po[i] += __shfl_xor(po[i], 2);
                po[i] += __shfl_xor(po[i], 4);
            }
            if (j8 == 0) {
                const float invd = 1.0f / den;
                #pragma unroll
                for (int i4 = 0; i4 < 4; ++i4)
                    *(float4*)&QP[q_][h_ * DHH + 4 * i4] =
                        make_float4(po[4*i4+0]*invd, po[4*i4+1]*invd,
                                    po[4*i4+2]*invd, po[4*i4+3]*invd);
            }
        }
        __syncthreads();

        // ---- P8: @Wo + residual + LayerNorm -> M1 ----
        {
            float orow[DD];
            #pragma unroll
            for (int d4 = 0; d4 < 8; ++d4)
                *(float4*)&orow[4 * d4] = F4(&QP[mq][4 * d4]);
            float x0 = p.bo[c2], x1 = p.bo[c2 + 1];
            #pragma unroll
            for (int d4 = 0; d4 < 8; ++d4) {
                float4 w0 = F4(&p.Wo[c2 * DD + 4 * d4]);
                float4 w1 = F4(&p.Wo[(c2 + 1) * DD + 4 * d4]);
                x0 += orow[4*d4]*w0.x + orow[4*d4+1]*w0.y + orow[4*d4+2]*w0.z + orow[4*d4+3]*w0.w;
                x1 += orow[4*d4]*w1.x + orow[4*d4+1]*w1.y + orow[4*d4+2]*w1.z + orow[4*d4+3]*w1.w;
            }
            float2 m0v = F2(&M0[mq][c2]);
            x0 += m0v.x; x1 += m0v.y;
            float s1 = x0 + x1;
            s1 += __shfl_xor(s1, 1); s1 += __shfl_xor(s1, 2);
            s1 += __shfl_xor(s1, 4); s1 += __shfl_xor(s1, 8);
            float mu = s1 * (1.0f / DD);
            float d0 = x0 - mu, d1 = x1 - mu;
            float s2 = d0*d0 + d1*d1;
            s2 += __shfl_xor(s2, 1); s2 += __shfl_xor(s2, 2);
            s2 += __shfl_xor(s2, 4); s2 += __shfl_xor(s2, 8);
            float rs = rsqrtf(s2 * (1.0f / DD) + 1e-5f);
            float y0 = d0 * rs * p.ln_g[c2]     + p.ln_b[c2];
            float y1 = d1 * rs * p.ln_g[c2 + 1] + p.ln_b[c2 + 1];
            *(float2*)&M1[mq][c2] = make_float2(y0, y1);
        }
        __syncthreads();

        // ---- P9: macro agg = A_ma @ M1 -> QW rows 0..15 ----
        {
            float a0 = 0.f, a1 = 0.f;
            #pragma unroll
            for (int n4 = 0; n4 < 4; ++n4) {
                float4 am = F4(&p.A_ma[mq * NMA + 4 * n4]);
                float2 m0 = F2(&M1[4*n4+0][c2]);
                float2 m1 = F2(&M1[4*n4+1][c2]);
                float2 m2 = F2(&M1[4*n4+2][c2]);
                float2 m3 = F2(&M1[4*n4+3][c2]);
                a0 += am.x*m0.x + am.y*m1.x + am.z*m2.x + am.w*m3.x;
                a1 += am.x*m0.y + am.y*m1.y + am.z*m2.y + am.w*m3.y;
            }
            *(float2*)&QW[mq][c2] = make_float2(a0, a1);
        }
        __syncthreads();

        // ---- P10: macro automata update -> M0 ----
        {
            float mrow[DD], arow[DD];
            #pragma unroll
            for (int d4 = 0; d4 < 8; ++d4) {
                *(float4*)&mrow[4 * d4] = F4(&M1[mq][4 * d4]);
                *(float4*)&arow[4 * d4] = F4(&QW[mq][4 * d4]);
            }
            float u0 = p.b_ma[c2], u1 = p.b_ma[c2 + 1];
            #pragma unroll
            for (int d = 0; d < DD; ++d) {
                float2 tv  = F2(&Tma[d][c2]);
                float2 wsv = F2(&p.Ws_ma[d * DD + c2]);
                float2 wav = F2(&p.Wa_ma[d * DD + c2]);
                u0 += mrow[d]*(tv.x + wsv.x) + arow[d]*wav.x;
                u1 += mrow[d]*(tv.y + wsv.y) + arow[d]*wav.y;
            }
            float2 ownm = F2(&M1[mq][c2]);
            float v0 = ownm.x + 0.1f * fast_tanh(u0);
            float v1 = ownm.y + 0.1f * fast_tanh(u1);
            float ssq = v0*v0 + v1*v1;
            ssq += __shfl_xor(ssq, 1); ssq += __shfl_xor(ssq, 2);
            ssq += __shfl_xor(ssq, 4); ssq += __shfl_xor(ssq, 8);
            float inv = 1.0f / (sqrtf(ssq) + 1e-6f);
            *(float2*)&M0[mq][c2] = make_float2(v0 * inv, v1 * inv);
        }
        __syncthreads();

        // ---- P11: macro trace update ----
        {
            float t0=0.f,t1=0.f,t2=0.f,t3=0.f;
            #pragma unroll
            for (int n = 0; n < NMA; ++n) {
                float pd = M1[n][dtr];
                float4 v = F4(&M0[n][e4]);
                t0 += pd*v.x; t1 += pd*v.y; t2 += pd*v.z; t3 += pd*v.w;
            }
            float4 tv = F4(&Tma[dtr][e4]);
            tv.x = 0.95f*tv.x + (0.05f/NMA)*t0;
            tv.y = 0.95f*tv.y + (0.05f/NMA)*t1;
            tv.z = 0.95f*tv.z + (0.05f/NMA)*t2;
            tv.w = 0.95f*tv.w + (0.05f/NMA)*t3;
            *(float4*)&Tma[dtr][e4] = tv;
        }
        // swap ping/pong
        { float (*tmp)[SP] = Scur; Scur = Snxt; Snxt = tmp; }
        __syncthreads();
    }

    // ---------------- energy (only final step's value persists) ----------------
    const size_t NB = gridDim.x;
    const size_t o1 = NB * (NMI * DD);
    const size_t o2 = o1 + NB * (NMA * DD);
    const size_t o3 = o2 + NB * (DD * DD);
    const size_t o4 = o3 + NB * (DD * DD);

    if (nsteps > 0) {
        const int e0 = (t & 3) * 16;
        float rowf[DD];
        #pragma unroll
        for (int d4 = 0; d4 < 8; ++d4)
            *(float4*)&rowf[4 * d4] = F4(&Scur[r][4 * d4]);
        float h16[16];
        #pragma unroll
        for (int i4 = 0; i4 < 4; ++i4)
            *(float4*)&h16[4 * i4] = F4(&p.be1[e0 + 4 * i4]);
        #pragma unroll
        for (int d = 0; d < DD; ++d) {
            float sd = rowf[d];
            #pragma unroll
            for (int i4 = 0; i4 < 4; ++i4) {
                float4 w = F4(&p.We1[d * EH + e0 + 4 * i4]);
                h16[4*i4+0] += sd*w.x; h16[4*i4+1] += sd*w.y;
                h16[4*i4+2] += sd*w.z; h16[4*i4+3] += sd*w.w;
            }
        }
        float val = 0.f;
        #pragma unroll
        for (int i = 0; i < 16; ++i)
            val += fast_tanh(h16[i]) * p.We2[e0 + i];
        val += __shfl_xor(val, 1); val += __shfl_xor(val, 2);
        if (s == 0) misc[r] = val;
        __syncthreads();
        if (t < 64) {
            float v = misc[t];
            v += __shfl_xor(v, 1);  v += __shfl_xor(v, 2);
            v += __shfl_xor(v, 4);  v += __shfl_xor(v, 8);
            v += __shfl_xor(v, 16); v += __shfl_xor(v, 32);
            if (t == 0) p.out[o4 + bid] = p.be2[0] + v * (1.0f / NMI);
        }
    } else {
        if (t == 0) p.out[o4 + bid] = 0.f;
    }

    // ---------------- stores ----------------
    {
        float* g = p.out + (size_t)bid * (NMI * DD) + r * DD + cs;
        *(float4*)(g)     = F4(&Scur[r][cs]);
        *(float4*)(g + 4) = F4(&Scur[r][cs + 4]);
    }
    {
        float* g = p.out + o1 + (size_t)bid * (NMA * DD) + mq * DD + c2;
        *(float2*)g = F2(&M0[mq][c2]);
    }
    {
        float* g = p.out + o2 + (size_t)bid * (DD * DD) + dtr * DD + e4;
        *(float4*)g = F4(&Tmi[dtr][e4]);
        g = p.out + o3 + (size_t)bid * (DD * DD) + dtr * DD + e4;
        *(float4*)g = F4(&Tma[dtr][e4]);
    }
}

extern "C" void kernel_launch(void* const* d_in, const int* in_sizes, int n_in,
                              void* d_out, int out_size, void* d_ws, size_t ws_size,
                              hipStream_t stream) {
    (void)n_in; (void)out_size; (void)d_ws; (void)ws_size;
    HMParams p;
    p.micro  = (const float*)d_in[0];
    p.macro_ = (const float*)d_in[1];
    p.tmi    = (const float*)d_in[2];
    p.tma    = (const float*)d_in[3];
    p.W_td   = (const float*)d_in[4];
    p.b_td   = (const float*)d_in[5];
    p.ln_g   = (const float*)d_in[6];
    p.ln_b   = (const float*)d_in[7];
    p.Wqkv   = (const float*)d_in[8];
    p.bqkv   = (const float*)d_in[9];
    p.Wo     = (const float*)d_in[10];
    p.bo     = (const float*)d_in[11];
    p.A_mi   = (const float*)d_in[12];
    p.Ws_mi  = (const float*)d_in[13];
    p.Wa_mi  = (const float*)d_in[14];
    p.b_mi   = (const float*)d_in[15];
    p.A_ma   = (const float*)d_in[16];
    p.Ws_ma  = (const float*)d_in[17];
    p.Wa_ma  = (const float*)d_in[18];
    p.b_ma   = (const float*)d_in[19];
    p.We1    = (const float*)d_in[20];
    p.be1    = (const float*)d_in[21];
    p.We2    = (const float*)d_in[22];
    p.be2    = (const float*)d_in[23];
    p.steps  = (const int*)d_in[24];
    p.out    = (float*)d_out;
    const int B = in_sizes[0] / (NMI * DD);
    hipLaunchKernelGGL(hm_fused, dim3(B), dim3(256), 0, stream, p);
}

// Round 3
// 6950.961 us; speedup vs baseline: 1.1066x; 1.1066x over previous
//
#include <hip/hip_runtime.h>
#include <math.h>

// HierarchicalManifold, v3: fused, 256 threads (4 waves) per batch element.
// Key change vs v2: (a) amdgpu_waves_per_eu(4,4) pins the VGPR budget to 128
// (v2's launch_bounds(256,4) let the scheduler target 8 waves/EU -> 64 VGPRs
// -> 18.7 GB of scratch spill traffic); (b) no per-thread 32-float row arrays:
// row operands stream from LDS as float4 temps, accumulators are <= 16 floats.
//
// Thread roles (t = 0..255):
//   micro-row ops : r = t>>2 (0..63), s = t&3, cols cs = 8s..8s+7
//   trace/qw ops  : dtr = t>>3 (0..31), j8 = t&7, cols e4 = 4*j8
//   macro ops     : mq = t>>4 (0..15), mj = t&15, cols c2 = 2*mj
//   attn ops      : hq = t>>3 (0..31) = (h,q), k in {j8, j8+8, ..., j8+56}

#define NMI 64
#define NMA 16
#define DD  32
#define DHH 16
#define EH  64
#define SP  36    // padded LDS stride

#define F4(p_) (*(const float4*)(p_))
#define F2(p_) (*(const float2*)(p_))

// acc[0..7] += s * ptr[0..7]  (ptr 16B-aligned)
#define FMA8(acc, sval, ptr_) do { \
    const float* _p = (const float*)(ptr_); \
    float4 _a = F4(_p); float4 _b = F4(_p + 4); \
    const float _s = (sval); \
    acc[0] += _s*_a.x; acc[1] += _s*_a.y; acc[2] += _s*_a.z; acc[3] += _s*_a.w; \
    acc[4] += _s*_b.x; acc[5] += _s*_b.y; acc[6] += _s*_b.z; acc[7] += _s*_b.w; \
} while(0)

struct HMParams {
    const float* micro; const float* macro_; const float* tmi; const float* tma;
    const float* W_td; const float* b_td; const float* ln_g; const float* ln_b;
    const float* Wqkv; const float* bqkv; const float* Wo; const float* bo;
    const float* A_mi; const float* Ws_mi; const float* Wa_mi; const float* b_mi;
    const float* A_ma; const float* Ws_ma; const float* Wa_ma; const float* b_ma;
    const float* We1; const float* be1; const float* We2; const float* be2;
    const int* steps;
    float* out;
};

__device__ __forceinline__ float fast_tanh(float x) {
    float e = __expf(2.0f * x);
    return 1.0f - 2.0f / (e + 1.0f);
}

__global__ void __launch_bounds__(256)
__attribute__((amdgpu_waves_per_eu(4, 4)))
hm_fused(HMParams p) {
    const int bid = blockIdx.x;
    const int t   = threadIdx.x;

    __shared__ float SA[NMI][SP];     // micro state ping
    __shared__ float SB[NMI][SP];     // micro state pong (agg scratch, then vp)
    __shared__ float Tmi[DD][DD];
    __shared__ float Tma[DD][DD];
    __shared__ float M0[NMA][SP];     // macro state
    __shared__ float M1[NMA][SP];     // post-LN macro
    __shared__ float QP[NMA][SP];     // qp, then attn-out
    __shared__ float QW[DD][SP];      // TW in P4; qw in P6/P7; AG rows 0..15 in P9/P10
    __shared__ float misc[64];        // colmean/bias | qb[32] | energy partials

    const int r   = t >> 2;
    const int s   = t & 3;
    const int cs  = s * 8;
    const int dtr = t >> 3;
    const int j8  = t & 7;
    const int e4  = j8 * 4;
    const int mq  = t >> 4;
    const int mj  = t & 15;
    const int c2  = mj * 2;

    // ---------------- load ----------------
    {
        const float* g = p.micro + (size_t)bid * (NMI * DD) + r * DD + cs;
        *(float4*)&SA[r][cs]     = F4(g);
        *(float4*)&SA[r][cs + 4] = F4(g + 4);
        const float* gt = p.tmi + (size_t)bid * (DD * DD) + dtr * DD + e4;
        *(float4*)&Tmi[dtr][e4] = F4(gt);
        gt = p.tma + (size_t)bid * (DD * DD) + dtr * DD + e4;
        *(float4*)&Tma[dtr][e4] = F4(gt);
        if (t < 128) {
            int q_ = t >> 3, c4 = (t & 7) * 4;
            *(float4*)&M0[q_][c4] =
                F4(p.macro_ + (size_t)bid * (NMA * DD) + q_ * DD + c4);
        }
    }
    const int nsteps = p.steps[0];
    __syncthreads();

    float (*Scur)[SP] = SA;
    float (*Snxt)[SP] = SB;

    for (int step = 0; step < nsteps; ++step) {
        // ---- P1: macro column means ----
        if (t < DD) {
            float a = 0.f;
            #pragma unroll
            for (int n = 0; n < NMA; ++n) a += M0[n][t];
            misc[t] = a * (1.0f / NMA);
        }
        __syncthreads();
        // ---- P2: 0.1 * (colmean @ W_td^T + b_td) ----
        if (t < DD) {
            float a = p.b_td[t];
            #pragma unroll
            for (int d4 = 0; d4 < 8; ++d4) {
                float4 w = F4(&p.W_td[t * DD + 4 * d4]);
                float4 m = F4(&misc[4 * d4]);
                a += m.x*w.x + m.y*w.y + m.z*w.z + m.w*w.w;
            }
            misc[DD + t] = 0.1f * a;
        }
        __syncthreads();
        // ---- P3: micro += bias (in place); TW = Tmi + Ws_mi -> QW ----
        {
            float4 b0 = F4(&misc[DD + cs]), b1 = F4(&misc[DD + cs + 4]);
            float4 v0 = F4(&Scur[r][cs]),   v1 = F4(&Scur[r][cs + 4]);
            v0.x += b0.x; v0.y += b0.y; v0.z += b0.z; v0.w += b0.w;
            v1.x += b1.x; v1.y += b1.y; v1.z += b1.z; v1.w += b1.w;
            *(float4*)&Scur[r][cs]     = v0;
            *(float4*)&Scur[r][cs + 4] = v1;
            float4 tv = F4(&Tmi[dtr][e4]);
            float4 wv = F4(&p.Ws_mi[dtr * DD + e4]);
            tv.x += wv.x; tv.y += wv.y; tv.z += wv.z; tv.w += wv.w;
            *(float4*)&QW[dtr][e4] = tv;
        }
        __syncthreads();

        // ---- P4a: acc = b_mi + S_in@(Tmi+Ws); agg partial -> Snxt ----
        float accv[8];
        {
            {
                float4 b0 = F4(&p.b_mi[cs]), b1 = F4(&p.b_mi[cs + 4]);
                accv[0]=b0.x; accv[1]=b0.y; accv[2]=b0.z; accv[3]=b0.w;
                accv[4]=b1.x; accv[5]=b1.y; accv[6]=b1.z; accv[7]=b1.w;
            }
            #pragma unroll
            for (int d4 = 0; d4 < 8; ++d4) {
                float4 sv = F4(&Scur[r][4 * d4]);
                FMA8(accv, sv.x, &QW[4*d4+0][cs]);
                FMA8(accv, sv.y, &QW[4*d4+1][cs]);
                FMA8(accv, sv.z, &QW[4*d4+2][cs]);
                FMA8(accv, sv.w, &QW[4*d4+3][cs]);
            }
            float aggv[8] = {0,0,0,0,0,0,0,0};
            #pragma unroll 4
            for (int n4 = 0; n4 < 16; ++n4) {
                float4 a4 = F4(&p.A_mi[r * NMI + 4 * n4]);
                FMA8(aggv, a4.x, &Scur[4*n4+0][cs]);
                FMA8(aggv, a4.y, &Scur[4*n4+1][cs]);
                FMA8(aggv, a4.z, &Scur[4*n4+2][cs]);
                FMA8(aggv, a4.w, &Scur[4*n4+3][cs]);
            }
            *(float4*)&Snxt[r][cs]     = make_float4(aggv[0],aggv[1],aggv[2],aggv[3]);
            *(float4*)&Snxt[r][cs + 4] = make_float4(aggv[4],aggv[5],aggv[6],aggv[7]);
        }
        __syncthreads();
        // ---- P4c: acc += agg@Wa; new = l2norm(S_in + 0.1*tanh(acc)) -> Snxt ----
        {
            #pragma unroll 2
            for (int d4 = 0; d4 < 8; ++d4) {
                float4 av = F4(&Snxt[r][4 * d4]);
                FMA8(accv, av.x, &p.Wa_mi[(4*d4+0) * DD + cs]);
                FMA8(accv, av.y, &p.Wa_mi[(4*d4+1) * DD + cs]);
                FMA8(accv, av.z, &p.Wa_mi[(4*d4+2) * DD + cs]);
                FMA8(accv, av.w, &p.Wa_mi[(4*d4+3) * DD + cs]);
            }
            float own[8];
            {
                float4 o0 = F4(&Scur[r][cs]), o1 = F4(&Scur[r][cs + 4]);
                own[0]=o0.x; own[1]=o0.y; own[2]=o0.z; own[3]=o0.w;
                own[4]=o1.x; own[5]=o1.y; own[6]=o1.z; own[7]=o1.w;
            }
            float vv[8]; float ss = 0.f;
            #pragma unroll
            for (int j = 0; j < 8; ++j) {
                float v_ = own[j] + 0.1f * fast_tanh(accv[j]);
                vv[j] = v_; ss += v_ * v_;
            }
            ss += __shfl_xor(ss, 1); ss += __shfl_xor(ss, 2);
            float inv = 1.0f / (sqrtf(ss) + 1e-6f);
            #pragma unroll
            for (int j = 0; j < 8; ++j) vv[j] *= inv;
            __syncthreads();   // all reads of agg scratch done before overwrite
            *(float4*)&Snxt[r][cs]     = make_float4(vv[0],vv[1],vv[2],vv[3]);
            *(float4*)&Snxt[r][cs + 4] = make_float4(vv[4],vv[5],vv[6],vv[7]);
        }
        __syncthreads();

        // ---- P5: micro trace update + qp projection ----
        {
            float t0=0.f,t1=0.f,t2=0.f,t3=0.f;
            #pragma unroll 4
            for (int n = 0; n < NMI; ++n) {
                float pd = Scur[n][dtr];
                float4 v = F4(&Snxt[n][e4]);
                t0 += pd*v.x; t1 += pd*v.y; t2 += pd*v.z; t3 += pd*v.w;
            }
            float4 tv = F4(&Tmi[dtr][e4]);
            tv.x = 0.95f*tv.x + (0.05f/NMI)*t0;
            tv.y = 0.95f*tv.y + (0.05f/NMI)*t1;
            tv.z = 0.95f*tv.z + (0.05f/NMI)*t2;
            tv.w = 0.95f*tv.w + (0.05f/NMI)*t3;
            *(float4*)&Tmi[dtr][e4] = tv;
        }
        {
            float q0 = p.bqkv[c2], q1 = p.bqkv[c2 + 1];
            #pragma unroll
            for (int d4 = 0; d4 < 8; ++d4) {
                float4 m  = F4(&M0[mq][4 * d4]);
                float4 w0 = F4(&p.Wqkv[c2 * DD + 4 * d4]);
                float4 w1 = F4(&p.Wqkv[(c2 + 1) * DD + 4 * d4]);
                q0 += m.x*w0.x + m.y*w0.y + m.z*w0.z + m.w*w0.w;
                q1 += m.x*w1.x + m.y*w1.y + m.z*w1.z + m.w*w1.w;
            }
            *(float2*)&QP[mq][c2] = make_float2(q0, q1);
        }
        __syncthreads();

        // ---- P6: vp -> Scur; qw = 0.25*(qp@Wk) -> QW; qb -> misc ----
        {
            float vv[8];
            {
                float4 b0 = F4(&p.bqkv[2*DD + cs]), b1 = F4(&p.bqkv[2*DD + cs + 4]);
                vv[0]=b0.x; vv[1]=b0.y; vv[2]=b0.z; vv[3]=b0.w;
                vv[4]=b1.x; vv[5]=b1.y; vv[6]=b1.z; vv[7]=b1.w;
            }
            #pragma unroll 2
            for (int d4 = 0; d4 < 8; ++d4) {
                float4 sv = F4(&Snxt[r][4 * d4]);
                #pragma unroll
                for (int j = 0; j < 8; ++j) {
                    float4 w = F4(&p.Wqkv[(2*DD + cs + j) * DD + 4 * d4]);
                    vv[j] += sv.x*w.x + sv.y*w.y + sv.z*w.z + sv.w*w.w;
                }
            }
            *(float4*)&Scur[r][cs]     = make_float4(vv[0],vv[1],vv[2],vv[3]);
            *(float4*)&Scur[r][cs + 4] = make_float4(vv[4],vv[5],vv[6],vv[7]);
        }
        {
            const int h_ = dtr >> 4, q_ = dtr & 15;
            float w0=0.f,w1=0.f,w2=0.f,w3=0.f,qb=0.f;
            #pragma unroll
            for (int e4i = 0; e4i < 4; ++e4i) {
                float4 qv = F4(&QP[q_][h_ * DHH + 4 * e4i]);
                float4 w;
                w = F4(&p.Wqkv[(DD + h_*DHH + 4*e4i + 0) * DD + e4]);
                w0 += qv.x*w.x; w1 += qv.x*w.y; w2 += qv.x*w.z; w3 += qv.x*w.w;
                w = F4(&p.Wqkv[(DD + h_*DHH + 4*e4i + 1) * DD + e4]);
                w0 += qv.y*w.x; w1 += qv.y*w.y; w2 += qv.y*w.z; w3 += qv.y*w.w;
                w = F4(&p.Wqkv[(DD + h_*DHH + 4*e4i + 2) * DD + e4]);
                w0 += qv.z*w.x; w1 += qv.z*w.y; w2 += qv.z*w.z; w3 += qv.z*w.w;
                w = F4(&p.Wqkv[(DD + h_*DHH + 4*e4i + 3) * DD + e4]);
                w0 += qv.w*w.x; w1 += qv.w*w.y; w2 += qv.w*w.z; w3 += qv.w*w.w;
                float4 bv = F4(&p.bqkv[DD + h_*DHH + 4*e4i]);
                qb += qv.x*bv.x + qv.y*bv.y + qv.z*bv.z + qv.w*bv.w;
            }
            *(float4*)&QW[dtr][e4] =
                make_float4(0.25f*w0, 0.25f*w1, 0.25f*w2, 0.25f*w3);
            if (j8 == 0) misc[dtr] = 0.25f * qb;
        }
        __syncthreads();

        // ---- P7: scores + softmax + PV (8 threads per (h,q), k stride 8) ----
        {
            const int hq = dtr, h_ = hq >> 4, q_ = hq & 15;
            float qwr[DD];
            #pragma unroll
            for (int d4 = 0; d4 < 8; ++d4)
                *(float4*)&qwr[4 * d4] = F4(&QW[hq][4 * d4]);
            const float qb = misc[hq];
            float sc[8];
            #pragma unroll 2
            for (int kk = 0; kk < 8; ++kk) {
                const int k = j8 + 8 * kk;
                float a = qb;
                #pragma unroll
                for (int d4 = 0; d4 < 8; ++d4) {
                    float4 b4 = F4(&Snxt[k][4 * d4]);
                    a += qwr[4*d4]*b4.x + qwr[4*d4+1]*b4.y
                       + qwr[4*d4+2]*b4.z + qwr[4*d4+3]*b4.w;
                }
                sc[kk] = a;
            }
            float mx = sc[0];
            #pragma unroll
            for (int kk = 1; kk < 8; ++kk) mx = fmaxf(mx, sc[kk]);
            mx = fmaxf(mx, __shfl_xor(mx, 1));
            mx = fmaxf(mx, __shfl_xor(mx, 2));
            mx = fmaxf(mx, __shfl_xor(mx, 4));
            float den = 0.f;
            #pragma unroll
            for (int kk = 0; kk < 8; ++kk) { sc[kk] = __expf(sc[kk] - mx); den += sc[kk]; }
            den += __shfl_xor(den, 1); den += __shfl_xor(den, 2); den += __shfl_xor(den, 4);
            float po[16];
            #pragma unroll
            for (int i = 0; i < 16; ++i) po[i] = 0.f;
            #pragma unroll 2
            for (int kk = 0; kk < 8; ++kk) {
                const int k = j8 + 8 * kk;
                const float pv = sc[kk];
                #pragma unroll
                for (int i4 = 0; i4 < 4; ++i4) {
                    float4 v = F4(&Scur[k][h_ * DHH + 4 * i4]);   // vp
                    po[4*i4+0] += pv*v.x; po[4*i4+1] += pv*v.y;
                    po[4*i4+2] += pv*v.z; po[4*i4+3] += pv*v.w;
                }
            }
            #pragma unroll
            for (int i = 0; i < 16; ++i) {
                po[i] += __shfl_xor(po[i], 1);
                po[i] += __shfl_xor(po[i], 2);
                po[i] += __shfl_xor(po[i], 4);
            }
            if (j8 == 0) {
                const float invd = 1.0f / den;
                #pragma unroll
                for (int i4 = 0; i4 < 4; ++i4)
                    *(float4*)&QP[q_][h_ * DHH + 4 * i4] =
                        make_float4(po[4*i4+0]*invd, po[4*i4+1]*invd,
                                    po[4*i4+2]*invd, po[4*i4+3]*invd);
            }
        }
        __syncthreads();

        // ---- P8: @Wo + residual + LayerNorm -> M1 ----
        {
            float x0 = p.bo[c2], x1 = p.bo[c2 + 1];
            #pragma unroll
            for (int d4 = 0; d4 < 8; ++d4) {
                float4 o  = F4(&QP[mq][4 * d4]);
                float4 w0 = F4(&p.Wo[c2 * DD + 4 * d4]);
                float4 w1 = F4(&p.Wo[(c2 + 1) * DD + 4 * d4]);
                x0 += o.x*w0.x + o.y*w0.y + o.z*w0.z + o.w*w0.w;
                x1 += o.x*w1.x + o.y*w1.y + o.z*w1.z + o.w*w1.w;
            }
            float2 m0v = F2(&M0[mq][c2]);
            x0 += m0v.x; x1 += m0v.y;
            float s1 = x0 + x1;
            s1 += __shfl_xor(s1, 1); s1 += __shfl_xor(s1, 2);
            s1 += __shfl_xor(s1, 4); s1 += __shfl_xor(s1, 8);
            float mu = s1 * (1.0f / DD);
            float d0 = x0 - mu, d1 = x1 - mu;
            float s2 = d0*d0 + d1*d1;
            s2 += __shfl_xor(s2, 1); s2 += __shfl_xor(s2, 2);
            s2 += __shfl_xor(s2, 4); s2 += __shfl_xor(s2, 8);
            float rs = rsqrtf(s2 * (1.0f / DD) + 1e-5f);
            float y0 = d0 * rs * p.ln_g[c2]     + p.ln_b[c2];
            float y1 = d1 * rs * p.ln_g[c2 + 1] + p.ln_b[c2 + 1];
            *(float2*)&M1[mq][c2] = make_float2(y0, y1);
        }
        __syncthreads();

        // ---- P9: macro agg = A_ma @ M1 -> QW rows 0..15 ----
        {
            float a0 = 0.f, a1 = 0.f;
            #pragma unroll
            for (int n4 = 0; n4 < 4; ++n4) {
                float4 am = F4(&p.A_ma[mq * NMA + 4 * n4]);
                float2 m0 = F2(&M1[4*n4+0][c2]);
                float2 m1 = F2(&M1[4*n4+1][c2]);
                float2 m2 = F2(&M1[4*n4+2][c2]);
                float2 m3 = F2(&M1[4*n4+3][c2]);
                a0 += am.x*m0.x + am.y*m1.x + am.z*m2.x + am.w*m3.x;
                a1 += am.x*m0.y + am.y*m1.y + am.z*m2.y + am.w*m3.y;
            }
            *(float2*)&QW[mq][c2] = make_float2(a0, a1);
        }
        __syncthreads();

        // ---- P10: macro automata update -> M0 ----
        {
            float u0 = p.b_ma[c2], u1 = p.b_ma[c2 + 1];
            #pragma unroll 2
            for (int d4 = 0; d4 < 8; ++d4) {
                float4 m = F4(&M1[mq][4 * d4]);
                float4 a = F4(&QW[mq][4 * d4]);
                float2 tv, wsv, wav;
                tv = F2(&Tma[4*d4+0][c2]); wsv = F2(&p.Ws_ma[(4*d4+0)*DD + c2]);
                wav = F2(&p.Wa_ma[(4*d4+0)*DD + c2]);
                u0 += m.x*(tv.x+wsv.x) + a.x*wav.x; u1 += m.x*(tv.y+wsv.y) + a.x*wav.y;
                tv = F2(&Tma[4*d4+1][c2]); wsv = F2(&p.Ws_ma[(4*d4+1)*DD + c2]);
                wav = F2(&p.Wa_ma[(4*d4+1)*DD + c2]);
                u0 += m.y*(tv.x+wsv.x) + a.y*wav.x; u1 += m.y*(tv.y+wsv.y) + a.y*wav.y;
                tv = F2(&Tma[4*d4+2][c2]); wsv = F2(&p.Ws_ma[(4*d4+2)*DD + c2]);
                wav = F2(&p.Wa_ma[(4*d4+2)*DD + c2]);
                u0 += m.z*(tv.x+wsv.x) + a.z*wav.x; u1 += m.z*(tv.y+wsv.y) + a.z*wav.y;
                tv = F2(&Tma[4*d4+3][c2]); wsv = F2(&p.Ws_ma[(4*d4+3)*DD + c2]);
                wav = F2(&p.Wa_ma[(4*d4+3)*DD + c2]);
                u0 += m.w*(tv.x+wsv.x) + a.w*wav.x; u1 += m.w*(tv.y+wsv.y) + a.w*wav.y;
            }
            float2 ownm = F2(&M1[mq][c2]);
            float v0 = ownm.x + 0.1f * fast_tanh(u0);
            float v1 = ownm.y + 0.1f * fast_tanh(u1);
            float ssq = v0*v0 + v1*v1;
            ssq += __shfl_xor(ssq, 1); ssq += __shfl_xor(ssq, 2);
            ssq += __shfl_xor(ssq, 4); ssq += __shfl_xor(ssq, 8);
            float inv = 1.0f / (sqrtf(ssq) + 1e-6f);
            *(float2*)&M0[mq][c2] = make_float2(v0 * inv, v1 * inv);
        }
        __syncthreads();

        // ---- P11: macro trace update ----
        {
            float t0=0.f,t1=0.f,t2=0.f,t3=0.f;
            #pragma unroll
            for (int n = 0; n < NMA; ++n) {
                float pd = M1[n][dtr];
                float4 v = F4(&M0[n][e4]);
                t0 += pd*v.x; t1 += pd*v.y; t2 += pd*v.z; t3 += pd*v.w;
            }
            float4 tv = F4(&Tma[dtr][e4]);
            tv.x = 0.95f*tv.x + (0.05f/NMA)*t0;
            tv.y = 0.95f*tv.y + (0.05f/NMA)*t1;
            tv.z = 0.95f*tv.z + (0.05f/NMA)*t2;
            tv.w = 0.95f*tv.w + (0.05f/NMA)*t3;
            *(float4*)&Tma[dtr][e4] = tv;
        }
        // swap ping/pong
        { float (*tmp)[SP] = Scur; Scur = Snxt; Snxt = tmp; }
        __syncthreads();
    }

    // ---------------- energy (only final step's value persists) ----------------
    const size_t NB = gridDim.x;
    const size_t o1 = NB * (NMI * DD);
    const size_t o2 = o1 + NB * (NMA * DD);
    const size_t o3 = o2 + NB * (DD * DD);
    const size_t o4 = o3 + NB * (DD * DD);

    if (nsteps > 0) {
        const int e0 = (t & 3) * 16;
        float h16[16];
        #pragma unroll
        for (int i4 = 0; i4 < 4; ++i4)
            *(float4*)&h16[4 * i4] = F4(&p.be1[e0 + 4 * i4]);
        #pragma unroll 2
        for (int d4 = 0; d4 < 8; ++d4) {
            float4 sv = F4(&Scur[r][4 * d4]);
            #pragma unroll
            for (int i4 = 0; i4 < 4; ++i4) {
                float4 w0 = F4(&p.We1[(4*d4+0) * EH + e0 + 4*i4]);
                float4 w1 = F4(&p.We1[(4*d4+1) * EH + e0 + 4*i4]);
                float4 w2 = F4(&p.We1[(4*d4+2) * EH + e0 + 4*i4]);
                float4 w3 = F4(&p.We1[(4*d4+3) * EH + e0 + 4*i4]);
                h16[4*i4+0] += sv.x*w0.x + sv.y*w1.x + sv.z*w2.x + sv.w*w3.x;
                h16[4*i4+1] += sv.x*w0.y + sv.y*w1.y + sv.z*w2.y + sv.w*w3.y;
                h16[4*i4+2] += sv.x*w0.z + sv.y*w1.z + sv.z*w2.z + sv.w*w3.z;
                h16[4*i4+3] += sv.x*w0.w + sv.y*w1.w + sv.z*w2.w + sv.w*w3.w;
            }
        }
        float val = 0.f;
        #pragma unroll
        for (int i = 0; i < 16; ++i)
            val += fast_tanh(h16[i]) * p.We2[e0 + i];
        val += __shfl_xor(val, 1); val += __shfl_xor(val, 2);
        if (s == 0) misc[r] = val;
        __syncthreads();
        if (t < 64) {
            float v = misc[t];
            v += __shfl_xor(v, 1);  v += __shfl_xor(v, 2);
            v += __shfl_xor(v, 4);  v += __shfl_xor(v, 8);
            v += __shfl_xor(v, 16); v += __shfl_xor(v, 32);
            if (t == 0) p.out[o4 + bid] = p.be2[0] + v * (1.0f / NMI);
        }
    } else {
        if (t == 0) p.out[o4 + bid] = 0.f;
    }

    // ---------------- stores ----------------
    {
        float* g = p.out + (size_t)bid * (NMI * DD) + r * DD + cs;
        *(float4*)(g)     = F4(&Scur[r][cs]);
        *(float4*)(g + 4) = F4(&Scur[r][cs + 4]);
    }
    {
        float* g = p.out + o1 + (size_t)bid * (NMA * DD) + mq * DD + c2;
        *(float2*)g = F2(&M0[mq][c2]);
    }
    {
        float* g = p.out + o2 + (size_t)bid * (DD * DD) + dtr * DD + e4;
        *(float4*)g = F4(&Tmi[dtr][e4]);
        g = p.out + o3 + (size_t)bid * (DD * DD) + dtr * DD + e4;
        *(float4*)g = F4(&Tma[dtr][e4]);
    }
}

extern "C" void kernel_launch(void* const* d_in, const int* in_sizes, int n_in,
                              void* d_out, int out_size, void* d_ws, size_t ws_size,
                              hipStream_t stream) {
    (void)n_in; (void)out_size; (void)d_ws; (void)ws_size;
    HMParams p;
    p.micro  = (const float*)d_in[0];
    p.macro_ = (const float*)d_in[1];
    p.tmi    = (const float*)d_in[2];
    p.tma    = (const float*)d_in[3];
    p.W_td   = (const float*)d_in[4];
    p.b_td   = (const float*)d_in[5];
    p.ln_g   = (const float*)d_in[6];
    p.ln_b   = (const float*)d_in[7];
    p.Wqkv   = (const float*)d_in[8];
    p.bqkv   = (const float*)d_in[9];
    p.Wo     = (const float*)d_in[10];
    p.bo     = (const float*)d_in[11];
    p.A_mi   = (const float*)d_in[12];
    p.Ws_mi  = (const float*)d_in[13];
    p.Wa_mi  = (const float*)d_in[14];
    p.b_mi   = (const float*)d_in[15];
    p.A_ma   = (const float*)d_in[16];
    p.Ws_ma  = (const float*)d_in[17];
    p.Wa_ma  = (const float*)d_in[18];
    p.b_ma   = (const float*)d_in[19];
    p.We1    = (const float*)d_in[20];
    p.be1    = (const float*)d_in[21];
    p.We2    = (const float*)d_in[22];
    p.be2    = (const float*)d_in[23];
    p.steps  = (const int*)d_in[24];
    p.out    = (float*)d_out;
    const int B = in_sizes[0] / (NMI * DD);
    hipLaunchKernelGGL(hm_fused, dim3(B), dim3(256), 0, stream, p);
}

// Round 4
// 3522.755 us; speedup vs baseline: 2.1835x; 1.9732x over previous
//
#include <hip/hip_runtime.h>
#include <math.h>

// HierarchicalManifold, v4: fused, 256 threads (4 waves) per batch element.
// v2/v3 lost 17 GB to register-spill scratch: the allocator targets 64 VGPRs
// (8 waves/EU) and v3's P7 held ~56 live floats. v4 makes 64 VGPRs
// structurally sufficient: every phase's live set <= ~28 floats, all register
// arrays fully unrolled (no runtime indices -> no localMem).
//
// Thread roles (t = 0..255):
//   micro-row ops : r = t>>2 (0..63), s = t&3, cols cs = 8s..8s+7
//   trace/qw ops  : dtr = t>>3 (0..31), j8 = t&7, cols e4 = 4*j8
//   macro ops     : mq = t>>4 (0..15), mj = t&15, cols c2 = 2*mj
//   attn ops      : hq = dtr (0..31) = (h,q), k in {j8, j8+8, ..., j8+56}

#define NMI 64
#define NMA 16
#define DD  32
#define DHH 16
#define EH  64
#define SP  36    // padded LDS stride

#define F4(p_) (*(const float4*)(p_))
#define F2(p_) (*(const float2*)(p_))

// acc[0..7] += s * ptr[0..7]  (ptr 16B-aligned)
#define FMA8(acc, sval, ptr_) do { \
    const float* _p = (const float*)(ptr_); \
    float4 _a = F4(_p); float4 _b = F4(_p + 4); \
    const float _s = (sval); \
    acc[0] += _s*_a.x; acc[1] += _s*_a.y; acc[2] += _s*_a.z; acc[3] += _s*_a.w; \
    acc[4] += _s*_b.x; acc[5] += _s*_b.y; acc[6] += _s*_b.z; acc[7] += _s*_b.w; \
} while(0)

struct HMParams {
    const float* micro; const float* macro_; const float* tmi; const float* tma;
    const float* W_td; const float* b_td; const float* ln_g; const float* ln_b;
    const float* Wqkv; const float* bqkv; const float* Wo; const float* bo;
    const float* A_mi; const float* Ws_mi; const float* Wa_mi; const float* b_mi;
    const float* A_ma; const float* Ws_ma; const float* Wa_ma; const float* b_ma;
    const float* We1; const float* be1; const float* We2; const float* be2;
    const int* steps;
    float* out;
};

__device__ __forceinline__ float fast_tanh(float x) {
    float e = __expf(2.0f * x);
    return 1.0f - 2.0f / (e + 1.0f);
}

__global__ __launch_bounds__(256) __attribute__((amdgpu_waves_per_eu(4, 4)))
void hm_fused(HMParams p) {
    const int bid = blockIdx.x;
    const int t   = threadIdx.x;

    __shared__ float SA[NMI][SP];     // micro state ping
    __shared__ float SB[NMI][SP];     // micro state pong (agg scratch, then vp)
    __shared__ float Tmi[DD][DD];
    __shared__ float Tma[DD][DD];
    __shared__ float M0[NMA][SP];     // macro state
    __shared__ float M1[NMA][SP];     // post-LN macro
    __shared__ float QP[NMA][SP];     // qp, then attn-out
    __shared__ float QW[DD][SP];      // TW in P4; qw in P6/P7; AG rows 0..15 in P9/P10
    __shared__ float misc[64];        // colmean/bias | qb[32] | energy partials

    const int r   = t >> 2;
    const int s   = t & 3;
    const int cs  = s * 8;
    const int dtr = t >> 3;
    const int j8  = t & 7;
    const int e4  = j8 * 4;
    const int mq  = t >> 4;
    const int mj  = t & 15;
    const int c2  = mj * 2;

    // ---------------- load ----------------
    {
        const float* g = p.micro + (size_t)bid * (NMI * DD) + r * DD + cs;
        *(float4*)&SA[r][cs]     = F4(g);
        *(float4*)&SA[r][cs + 4] = F4(g + 4);
        const float* gt = p.tmi + (size_t)bid * (DD * DD) + dtr * DD + e4;
        *(float4*)&Tmi[dtr][e4] = F4(gt);
        gt = p.tma + (size_t)bid * (DD * DD) + dtr * DD + e4;
        *(float4*)&Tma[dtr][e4] = F4(gt);
        if (t < 128) {
            int q_ = t >> 3, c4 = (t & 7) * 4;
            *(float4*)&M0[q_][c4] =
                F4(p.macro_ + (size_t)bid * (NMA * DD) + q_ * DD + c4);
        }
    }
    const int nsteps = p.steps[0];
    __syncthreads();

    float (*Scur)[SP] = SA;
    float (*Snxt)[SP] = SB;

    for (int step = 0; step < nsteps; ++step) {
        // ---- P1: macro column means ----
        if (t < DD) {
            float a = 0.f;
            #pragma unroll
            for (int n = 0; n < NMA; ++n) a += M0[n][t];
            misc[t] = a * (1.0f / NMA);
        }
        __syncthreads();
        // ---- P2: 0.1 * (colmean @ W_td^T + b_td) ----
        if (t < DD) {
            float a = p.b_td[t];
            #pragma unroll
            for (int d4 = 0; d4 < 8; ++d4) {
                float4 w = F4(&p.W_td[t * DD + 4 * d4]);
                float4 m = F4(&misc[4 * d4]);
                a += m.x*w.x + m.y*w.y + m.z*w.z + m.w*w.w;
            }
            misc[DD + t] = 0.1f * a;
        }
        __syncthreads();
        // ---- P3: micro += bias (in place); TW = Tmi + Ws_mi -> QW ----
        {
            float4 b0 = F4(&misc[DD + cs]), b1 = F4(&misc[DD + cs + 4]);
            float4 v0 = F4(&Scur[r][cs]),   v1 = F4(&Scur[r][cs + 4]);
            v0.x += b0.x; v0.y += b0.y; v0.z += b0.z; v0.w += b0.w;
            v1.x += b1.x; v1.y += b1.y; v1.z += b1.z; v1.w += b1.w;
            *(float4*)&Scur[r][cs]     = v0;
            *(float4*)&Scur[r][cs + 4] = v1;
            float4 tv = F4(&Tmi[dtr][e4]);
            float4 wv = F4(&p.Ws_mi[dtr * DD + e4]);
            tv.x += wv.x; tv.y += wv.y; tv.z += wv.z; tv.w += wv.w;
            *(float4*)&QW[dtr][e4] = tv;
        }
        __syncthreads();

        // ---- P4a: acc = b_mi + S_in@(Tmi+Ws)  (acc kept in regs, 8 floats) ----
        float accv[8];
        {
            {
                float4 b0 = F4(&p.b_mi[cs]), b1 = F4(&p.b_mi[cs + 4]);
                accv[0]=b0.x; accv[1]=b0.y; accv[2]=b0.z; accv[3]=b0.w;
                accv[4]=b1.x; accv[5]=b1.y; accv[6]=b1.z; accv[7]=b1.w;
            }
            #pragma unroll
            for (int d4 = 0; d4 < 8; ++d4) {
                float4 sv = F4(&Scur[r][4 * d4]);
                FMA8(accv, sv.x, &QW[4*d4+0][cs]);
                FMA8(accv, sv.y, &QW[4*d4+1][cs]);
                FMA8(accv, sv.z, &QW[4*d4+2][cs]);
                FMA8(accv, sv.w, &QW[4*d4+3][cs]);
            }
            // agg partial -> Snxt (scratch)
            float aggv[8] = {0,0,0,0,0,0,0,0};
            #pragma unroll
            for (int n4 = 0; n4 < 16; ++n4) {
                float4 a4 = F4(&p.A_mi[r * NMI + 4 * n4]);
                FMA8(aggv, a4.x, &Scur[4*n4+0][cs]);
                FMA8(aggv, a4.y, &Scur[4*n4+1][cs]);
                FMA8(aggv, a4.z, &Scur[4*n4+2][cs]);
                FMA8(aggv, a4.w, &Scur[4*n4+3][cs]);
            }
            *(float4*)&Snxt[r][cs]     = make_float4(aggv[0],aggv[1],aggv[2],aggv[3]);
            *(float4*)&Snxt[r][cs + 4] = make_float4(aggv[4],aggv[5],aggv[6],aggv[7]);
        }
        __syncthreads();
        // ---- P4c: acc += agg@Wa; new = l2norm(S_in + 0.1*tanh(acc)) -> Snxt ----
        {
            #pragma unroll
            for (int d4 = 0; d4 < 8; ++d4) {
                float4 av = F4(&Snxt[r][4 * d4]);
                FMA8(accv, av.x, &p.Wa_mi[(4*d4+0) * DD + cs]);
                FMA8(accv, av.y, &p.Wa_mi[(4*d4+1) * DD + cs]);
                FMA8(accv, av.z, &p.Wa_mi[(4*d4+2) * DD + cs]);
                FMA8(accv, av.w, &p.Wa_mi[(4*d4+3) * DD + cs]);
            }
            float vv[8]; float ss = 0.f;
            {
                float4 o0 = F4(&Scur[r][cs]), o1 = F4(&Scur[r][cs + 4]);
                vv[0] = o0.x + 0.1f * fast_tanh(accv[0]);
                vv[1] = o0.y + 0.1f * fast_tanh(accv[1]);
                vv[2] = o0.z + 0.1f * fast_tanh(accv[2]);
                vv[3] = o0.w + 0.1f * fast_tanh(accv[3]);
                vv[4] = o1.x + 0.1f * fast_tanh(accv[4]);
                vv[5] = o1.y + 0.1f * fast_tanh(accv[5]);
                vv[6] = o1.z + 0.1f * fast_tanh(accv[6]);
                vv[7] = o1.w + 0.1f * fast_tanh(accv[7]);
            }
            #pragma unroll
            for (int j = 0; j < 8; ++j) ss += vv[j] * vv[j];
            ss += __shfl_xor(ss, 1); ss += __shfl_xor(ss, 2);
            float inv = 1.0f / (sqrtf(ss) + 1e-6f);
            #pragma unroll
            for (int j = 0; j < 8; ++j) vv[j] *= inv;
            __syncthreads();   // all reads of agg scratch done before overwrite
            *(float4*)&Snxt[r][cs]     = make_float4(vv[0],vv[1],vv[2],vv[3]);
            *(float4*)&Snxt[r][cs + 4] = make_float4(vv[4],vv[5],vv[6],vv[7]);
        }
        __syncthreads();

        // ---- P5: micro trace update + qp projection ----
        {
            float t0=0.f,t1=0.f,t2=0.f,t3=0.f;
            #pragma unroll
            for (int n = 0; n < NMI; ++n) {
                float pd = Scur[n][dtr];
                float4 v = F4(&Snxt[n][e4]);
                t0 += pd*v.x; t1 += pd*v.y; t2 += pd*v.z; t3 += pd*v.w;
            }
            float4 tv = F4(&Tmi[dtr][e4]);
            tv.x = 0.95f*tv.x + (0.05f/NMI)*t0;
            tv.y = 0.95f*tv.y + (0.05f/NMI)*t1;
            tv.z = 0.95f*tv.z + (0.05f/NMI)*t2;
            tv.w = 0.95f*tv.w + (0.05f/NMI)*t3;
            *(float4*)&Tmi[dtr][e4] = tv;
        }
        {
            float q0 = p.bqkv[c2], q1 = p.bqkv[c2 + 1];
            #pragma unroll
            for (int d4 = 0; d4 < 8; ++d4) {
                float4 m  = F4(&M0[mq][4 * d4]);
                float4 w0 = F4(&p.Wqkv[c2 * DD + 4 * d4]);
                float4 w1 = F4(&p.Wqkv[(c2 + 1) * DD + 4 * d4]);
                q0 += m.x*w0.x + m.y*w0.y + m.z*w0.z + m.w*w0.w;
                q1 += m.x*w1.x + m.y*w1.y + m.z*w1.z + m.w*w1.w;
            }
            *(float2*)&QP[mq][c2] = make_float2(q0, q1);
        }
        __syncthreads();

        // ---- P6: vp -> Scur; qw = 0.25*(qp@Wk) -> QW; qb -> misc ----
        {
            float vv[8];
            {
                float4 b0 = F4(&p.bqkv[2*DD + cs]), b1 = F4(&p.bqkv[2*DD + cs + 4]);
                vv[0]=b0.x; vv[1]=b0.y; vv[2]=b0.z; vv[3]=b0.w;
                vv[4]=b1.x; vv[5]=b1.y; vv[6]=b1.z; vv[7]=b1.w;
            }
            #pragma unroll
            for (int d4 = 0; d4 < 8; ++d4) {
                float4 sv = F4(&Snxt[r][4 * d4]);
                #pragma unroll
                for (int j = 0; j < 8; ++j) {
                    float4 w = F4(&p.Wqkv[(2*DD + cs + j) * DD + 4 * d4]);
                    vv[j] += sv.x*w.x + sv.y*w.y + sv.z*w.z + sv.w*w.w;
                }
            }
            *(float4*)&Scur[r][cs]     = make_float4(vv[0],vv[1],vv[2],vv[3]);
            *(float4*)&Scur[r][cs + 4] = make_float4(vv[4],vv[5],vv[6],vv[7]);
        }
        {
            const int h_ = dtr >> 4, q_ = dtr & 15;
            float w0=0.f,w1=0.f,w2=0.f,w3=0.f,qb=0.f;
            #pragma unroll
            for (int e4i = 0; e4i < 4; ++e4i) {
                float4 qv = F4(&QP[q_][h_ * DHH + 4 * e4i]);
                float4 w;
                w = F4(&p.Wqkv[(DD + h_*DHH + 4*e4i + 0) * DD + e4]);
                w0 += qv.x*w.x; w1 += qv.x*w.y; w2 += qv.x*w.z; w3 += qv.x*w.w;
                w = F4(&p.Wqkv[(DD + h_*DHH + 4*e4i + 1) * DD + e4]);
                w0 += qv.y*w.x; w1 += qv.y*w.y; w2 += qv.y*w.z; w3 += qv.y*w.w;
                w = F4(&p.Wqkv[(DD + h_*DHH + 4*e4i + 2) * DD + e4]);
                w0 += qv.z*w.x; w1 += qv.z*w.y; w2 += qv.z*w.z; w3 += qv.z*w.w;
                w = F4(&p.Wqkv[(DD + h_*DHH + 4*e4i + 3) * DD + e4]);
                w0 += qv.w*w.x; w1 += qv.w*w.y; w2 += qv.w*w.z; w3 += qv.w*w.w;
                float4 bv = F4(&p.bqkv[DD + h_*DHH + 4*e4i]);
                qb += qv.x*bv.x + qv.y*bv.y + qv.z*bv.z + qv.w*bv.w;
            }
            *(float4*)&QW[dtr][e4] =
                make_float4(0.25f*w0, 0.25f*w1, 0.25f*w2, 0.25f*w3);
            if (j8 == 0) misc[dtr] = 0.25f * qb;
        }
        __syncthreads();

        // ---- P7: scores + softmax + PV (8 threads per (h,q), k stride 8) ----
        // Register-blocked: qw in halves of 16, PV dims in halves of 8.
        {
            const int hq = dtr, h_ = hq >> 4, q_ = hq & 15;
            const float qb = misc[hq];
            float sc[8];
            {
                float qh[16];
                #pragma unroll
                for (int i4 = 0; i4 < 4; ++i4)
                    *(float4*)&qh[4*i4] = F4(&QW[hq][4*i4]);
                #pragma unroll
                for (int kk = 0; kk < 8; ++kk) {
                    const int k = j8 + 8 * kk;
                    float a = qb;
                    #pragma unroll
                    for (int i4 = 0; i4 < 4; ++i4) {
                        float4 b4 = F4(&Snxt[k][4*i4]);
                        a += qh[4*i4]*b4.x + qh[4*i4+1]*b4.y
                           + qh[4*i4+2]*b4.z + qh[4*i4+3]*b4.w;
                    }
                    sc[kk] = a;
                }
                #pragma unroll
                for (int i4 = 0; i4 < 4; ++i4)
                    *(float4*)&qh[4*i4] = F4(&QW[hq][16 + 4*i4]);
                #pragma unroll
                for (int kk = 0; kk < 8; ++kk) {
                    const int k = j8 + 8 * kk;
                    float a = 0.f;
                    #pragma unroll
                    for (int i4 = 0; i4 < 4; ++i4) {
                        float4 b4 = F4(&Snxt[k][16 + 4*i4]);
                        a += qh[4*i4]*b4.x + qh[4*i4+1]*b4.y
                           + qh[4*i4+2]*b4.z + qh[4*i4+3]*b4.w;
                    }
                    sc[kk] += a;
                }
            }
            float mx = sc[0];
            #pragma unroll
            for (int kk = 1; kk < 8; ++kk) mx = fmaxf(mx, sc[kk]);
            mx = fmaxf(mx, __shfl_xor(mx, 1));
            mx = fmaxf(mx, __shfl_xor(mx, 2));
            mx = fmaxf(mx, __shfl_xor(mx, 4));
            float den = 0.f;
            #pragma unroll
            for (int kk = 0; kk < 8; ++kk) { sc[kk] = __expf(sc[kk] - mx); den += sc[kk]; }
            den += __shfl_xor(den, 1); den += __shfl_xor(den, 2); den += __shfl_xor(den, 4);
            const float invd = 1.0f / den;
            #pragma unroll
            for (int half = 0; half < 2; ++half) {
                float po[8] = {0,0,0,0,0,0,0,0};
                #pragma unroll
                for (int kk = 0; kk < 8; ++kk) {
                    const int k = j8 + 8 * kk;
                    const float pv = sc[kk];
                    float4 v0 = F4(&Scur[k][h_ * DHH + 8*half]);
                    float4 v1 = F4(&Scur[k][h_ * DHH + 8*half + 4]);
                    po[0] += pv*v0.x; po[1] += pv*v0.y; po[2] += pv*v0.z; po[3] += pv*v0.w;
                    po[4] += pv*v1.x; po[5] += pv*v1.y; po[6] += pv*v1.z; po[7] += pv*v1.w;
                }
                #pragma unroll
                for (int i = 0; i < 8; ++i) {
                    po[i] += __shfl_xor(po[i], 1);
                    po[i] += __shfl_xor(po[i], 2);
                    po[i] += __shfl_xor(po[i], 4);
                }
                if (j8 == 0) {
                    *(float4*)&QP[q_][h_ * DHH + 8*half] =
                        make_float4(po[0]*invd, po[1]*invd, po[2]*invd, po[3]*invd);
                    *(float4*)&QP[q_][h_ * DHH + 8*half + 4] =
                        make_float4(po[4]*invd, po[5]*invd, po[6]*invd, po[7]*invd);
                }
            }
        }
        __syncthreads();

        // ---- P8: @Wo + residual + LayerNorm -> M1 ----
        {
            float x0 = p.bo[c2], x1 = p.bo[c2 + 1];
            #pragma unroll
            for (int d4 = 0; d4 < 8; ++d4) {
                float4 o  = F4(&QP[mq][4 * d4]);
                float4 w0 = F4(&p.Wo[c2 * DD + 4 * d4]);
                float4 w1 = F4(&p.Wo[(c2 + 1) * DD + 4 * d4]);
                x0 += o.x*w0.x + o.y*w0.y + o.z*w0.z + o.w*w0.w;
                x1 += o.x*w1.x + o.y*w1.y + o.z*w1.z + o.w*w1.w;
            }
            float2 m0v = F2(&M0[mq][c2]);
            x0 += m0v.x; x1 += m0v.y;
            float s1 = x0 + x1;
            s1 += __shfl_xor(s1, 1); s1 += __shfl_xor(s1, 2);
            s1 += __shfl_xor(s1, 4); s1 += __shfl_xor(s1, 8);
            float mu = s1 * (1.0f / DD);
            float d0 = x0 - mu, d1 = x1 - mu;
            float s2 = d0*d0 + d1*d1;
            s2 += __shfl_xor(s2, 1); s2 += __shfl_xor(s2, 2);
            s2 += __shfl_xor(s2, 4); s2 += __shfl_xor(s2, 8);
            float rs = rsqrtf(s2 * (1.0f / DD) + 1e-5f);
            float y0 = d0 * rs * p.ln_g[c2]     + p.ln_b[c2];
            float y1 = d1 * rs * p.ln_g[c2 + 1] + p.ln_b[c2 + 1];
            *(float2*)&M1[mq][c2] = make_float2(y0, y1);
        }
        __syncthreads();

        // ---- P9: macro agg = A_ma @ M1 -> QW rows 0..15 ----
        {
            float a0 = 0.f, a1 = 0.f;
            #pragma unroll
            for (int n4 = 0; n4 < 4; ++n4) {
                float4 am = F4(&p.A_ma[mq * NMA + 4 * n4]);
                float2 m0 = F2(&M1[4*n4+0][c2]);
                float2 m1 = F2(&M1[4*n4+1][c2]);
                float2 m2 = F2(&M1[4*n4+2][c2]);
                float2 m3 = F2(&M1[4*n4+3][c2]);
                a0 += am.x*m0.x + am.y*m1.x + am.z*m2.x + am.w*m3.x;
                a1 += am.x*m0.y + am.y*m1.y + am.z*m2.y + am.w*m3.y;
            }
            *(float2*)&QW[mq][c2] = make_float2(a0, a1);
        }
        __syncthreads();

        // ---- P10: macro automata update -> M0 ----
        {
            float u0 = p.b_ma[c2], u1 = p.b_ma[c2 + 1];
            #pragma unroll
            for (int d4 = 0; d4 < 8; ++d4) {
                float4 m = F4(&M1[mq][4 * d4]);
                float4 a = F4(&QW[mq][4 * d4]);
                float2 tv, wsv, wav;
                tv = F2(&Tma[4*d4+0][c2]); wsv = F2(&p.Ws_ma[(4*d4+0)*DD + c2]);
                wav = F2(&p.Wa_ma[(4*d4+0)*DD + c2]);
                u0 += m.x*(tv.x+wsv.x) + a.x*wav.x; u1 += m.x*(tv.y+wsv.y) + a.x*wav.y;
                tv = F2(&Tma[4*d4+1][c2]); wsv = F2(&p.Ws_ma[(4*d4+1)*DD + c2]);
                wav = F2(&p.Wa_ma[(4*d4+1)*DD + c2]);
                u0 += m.y*(tv.x+wsv.x) + a.y*wav.x; u1 += m.y*(tv.y+wsv.y) + a.y*wav.y;
                tv = F2(&Tma[4*d4+2][c2]); wsv = F2(&p.Ws_ma[(4*d4+2)*DD + c2]);
                wav = F2(&p.Wa_ma[(4*d4+2)*DD + c2]);
                u0 += m.z*(tv.x+wsv.x) + a.z*wav.x; u1 += m.z*(tv.y+wsv.y) + a.z*wav.y;
                tv = F2(&Tma[4*d4+3][c2]); wsv = F2(&p.Ws_ma[(4*d4+3)*DD + c2]);
                wav = F2(&p.Wa_ma[(4*d4+3)*DD + c2]);
                u0 += m.w*(tv.x+wsv.x) + a.w*wav.x; u1 += m.w*(tv.y+wsv.y) + a.w*wav.y;
            }
            float2 ownm = F2(&M1[mq][c2]);
            float v0 = ownm.x + 0.1f * fast_tanh(u0);
            float v1 = ownm.y + 0.1f * fast_tanh(u1);
            float ssq = v0*v0 + v1*v1;
            ssq += __shfl_xor(ssq, 1); ssq += __shfl_xor(ssq, 2);
            ssq += __shfl_xor(ssq, 4); ssq += __shfl_xor(ssq, 8);
            float inv = 1.0f / (sqrtf(ssq) + 1e-6f);
            *(float2*)&M0[mq][c2] = make_float2(v0 * inv, v1 * inv);
        }
        __syncthreads();

        // ---- P11: macro trace update ----
        {
            float t0=0.f,t1=0.f,t2=0.f,t3=0.f;
            #pragma unroll
            for (int n = 0; n < NMA; ++n) {
                float pd = M1[n][dtr];
                float4 v = F4(&M0[n][e4]);
                t0 += pd*v.x; t1 += pd*v.y; t2 += pd*v.z; t3 += pd*v.w;
            }
            float4 tv = F4(&Tma[dtr][e4]);
            tv.x = 0.95f*tv.x + (0.05f/NMA)*t0;
            tv.y = 0.95f*tv.y + (0.05f/NMA)*t1;
            tv.z = 0.95f*tv.z + (0.05f/NMA)*t2;
            tv.w = 0.95f*tv.w + (0.05f/NMA)*t3;
            *(float4*)&Tma[dtr][e4] = tv;
        }
        // swap ping/pong
        { float (*tmp)[SP] = Scur; Scur = Snxt; Snxt = tmp; }
        __syncthreads();
    }

    // ---------------- energy (only final step's value persists) ----------------
    const size_t NB = gridDim.x;
    const size_t o1 = NB * (NMI * DD);
    const size_t o2 = o1 + NB * (NMA * DD);
    const size_t o3 = o2 + NB * (DD * DD);
    const size_t o4 = o3 + NB * (DD * DD);

    if (nsteps > 0) {
        const int e0 = (t & 3) * 16;
        float val = 0.f;
        // two passes of 8 hidden units each to cap live registers
        #pragma unroll
        for (int half = 0; half < 2; ++half) {
            float h8[8];
            *(float4*)&h8[0] = F4(&p.be1[e0 + 8*half]);
            *(float4*)&h8[4] = F4(&p.be1[e0 + 8*half + 4]);
            #pragma unroll
            for (int d4 = 0; d4 < 8; ++d4) {
                float4 sv = F4(&Scur[r][4 * d4]);
                FMA8(h8, sv.x, &p.We1[(4*d4+0) * EH + e0 + 8*half]);
                FMA8(h8, sv.y, &p.We1[(4*d4+1) * EH + e0 + 8*half]);
                FMA8(h8, sv.z, &p.We1[(4*d4+2) * EH + e0 + 8*half]);
                FMA8(h8, sv.w, &p.We1[(4*d4+3) * EH + e0 + 8*half]);
            }
            #pragma unroll
            for (int i = 0; i < 8; ++i)
                val += fast_tanh(h8[i]) * p.We2[e0 + 8*half + i];
        }
        val += __shfl_xor(val, 1); val += __shfl_xor(val, 2);
        if (s == 0) misc[r] = val;
        __syncthreads();
        if (t < 64) {
            float v = misc[t];
            v += __shfl_xor(v, 1);  v += __shfl_xor(v, 2);
            v += __shfl_xor(v, 4);  v += __shfl_xor(v, 8);
            v += __shfl_xor(v, 16); v += __shfl_xor(v, 32);
            if (t == 0) p.out[o4 + bid] = p.be2[0] + v * (1.0f / NMI);
        }
    } else {
        if (t == 0) p.out[o4 + bid] = 0.f;
    }

    // ---------------- stores ----------------
    {
        float* g = p.out + (size_t)bid * (NMI * DD) + r * DD + cs;
        *(float4*)(g)     = F4(&Scur[r][cs]);
        *(float4*)(g + 4) = F4(&Scur[r][cs + 4]);
    }
    {
        float* g = p.out + o1 + (size_t)bid * (NMA * DD) + mq * DD + c2;
        *(float2*)g = F2(&M0[mq][c2]);
    }
    {
        float* g = p.out + o2 + (size_t)bid * (DD * DD) + dtr * DD + e4;
        *(float4*)g = F4(&Tmi[dtr][e4]);
        g = p.out + o3 + (size_t)bid * (DD * DD) + dtr * DD + e4;
        *(float4*)g = F4(&Tma[dtr][e4]);
    }
}

extern "C" void kernel_launch(void* const* d_in, const int* in_sizes, int n_in,
                              void* d_out, int out_size, void* d_ws, size_t ws_size,
                              hipStream_t stream) {
    (void)n_in; (void)out_size; (void)d_ws; (void)ws_size;
    HMParams p;
    p.micro  = (const float*)d_in[0];
    p.macro_ = (const float*)d_in[1];
    p.tmi    = (const float*)d_in[2];
    p.tma    = (const float*)d_in[3];
    p.W_td   = (const float*)d_in[4];
    p.b_td   = (const float*)d_in[5];
    p.ln_g   = (const float*)d_in[6];
    p.ln_b   = (const float*)d_in[7];
    p.Wqkv   = (const float*)d_in[8];
    p.bqkv   = (const float*)d_in[9];
    p.Wo     = (const float*)d_in[10];
    p.bo     = (const float*)d_in[11];
    p.A_mi   = (const float*)d_in[12];
    p.Ws_mi  = (const float*)d_in[13];
    p.Wa_mi  = (const float*)d_in[14];
    p.b_mi   = (const float*)d_in[15];
    p.A_ma   = (const float*)d_in[16];
    p.Ws_ma  = (const float*)d_in[17];
    p.Wa_ma  = (const float*)d_in[18];
    p.b_ma   = (const float*)d_in[19];
    p.We1    = (const float*)d_in[20];
    p.be1    = (const float*)d_in[21];
    p.We2    = (const float*)d_in[22];
    p.be2    = (const float*)d_in[23];
    p.steps  = (const int*)d_in[24];
    p.out    = (float*)d_out;
    const int B = in_sizes[0] / (NMI * DD);
    hipLaunchKernelGGL(hm_fused, dim3(B), dim3(256), 0, stream, p);
}